// Round 9
// baseline (1154.692 us; speedup 1.0000x reference)
//
#include <hip/hip_runtime.h>

#define BB 16
#define NN 2048
#define FIN 6
#define MTOT (BB*NN)   // 32768

typedef unsigned short u16;
typedef __attribute__((ext_vector_type(8))) short  short8;
typedef __attribute__((ext_vector_type(4))) float  f32x4;

// ---- bf16 helpers ----------------------------------------------------------
__device__ inline float ldf(const u16* p) {
  unsigned u = ((unsigned)*p) << 16; float f; __builtin_memcpy(&f, &u, 4); return f;
}
__device__ inline u16 tobf(float v) {
  unsigned u; __builtin_memcpy(&u, &v, 4);
  u = (u + 0x7FFFu + ((u >> 16) & 1u)) >> 16;   // RNE
  return (u16)u;
}
__device__ inline void stf(u16* p, float v) { *p = tobf(v); }

// async global->LDS, 16 bytes per lane (dest = wave-uniform base + lane*16)
__device__ __forceinline__ void gload16(const u16* g, u16* l) {
  __builtin_amdgcn_global_load_lds(
      (const __attribute__((address_space(1))) void*)g,
      (__attribute__((address_space(3))) void*)l, 16, 0, 0);
}

// counted vmcnt wait: lgkm/exp don't-care (0xF70), vmcnt = N (N <= 15)
template <int N>
__device__ __forceinline__ void wait_vmcnt() {
  __builtin_amdgcn_s_waitcnt(0xF70 | N);
  __builtin_amdgcn_sched_barrier(0);
}

// ---------------------------------------------------------------------------
// partial row-sums of adj: dsum[b,i] += sum_{j in chunk} exp(-||x_i-x_j||^2)
// ---------------------------------------------------------------------------
__global__ __launch_bounds__(256) void k_dpart(const float* __restrict__ x,
                                               float* __restrict__ dsum) {
  __shared__ float xs[512][FIN];
  __shared__ float sqs[512];
  const int b = blockIdx.y;
  const int j0 = blockIdx.z * 512;
  const float* xb = x + (size_t)b * NN * FIN;
  for (int l = threadIdx.x; l < 512 * FIN; l += 256) ((float*)xs)[l] = xb[(size_t)j0 * FIN + l];
  __syncthreads();
  for (int j = threadIdx.x; j < 512; j += 256) {
    float s = 0.f;
#pragma unroll
    for (int f = 0; f < FIN; ++f) { float v = xs[j][f]; s = fmaf(v, v, s); }
    sqs[j] = s;
  }
  __syncthreads();
  const int i = blockIdx.x * 256 + threadIdx.x;
  float xi[FIN];
#pragma unroll
  for (int f = 0; f < FIN; ++f) xi[f] = xb[(size_t)i * FIN + f];
  float sqi = 0.f;
#pragma unroll
  for (int f = 0; f < FIN; ++f) sqi = fmaf(xi[f], xi[f], sqi);
  float a0 = 0.f, a1 = 0.f, a2 = 0.f, a3 = 0.f;
  for (int j = 0; j < 512; j += 4) {
#pragma unroll
    for (int u = 0; u < 4; ++u) {
      const int jj = j + u;
      float dot = 0.f;
#pragma unroll
      for (int f = 0; f < FIN; ++f) dot = fmaf(xs[jj][f], xi[f], dot);
      const float e = __expf(2.f * dot - sqi - sqs[jj]);
      if (u == 0) a0 += e; else if (u == 1) a1 += e; else if (u == 2) a2 += e; else a3 += e;
    }
  }
  atomicAdd(&dsum[b * NN + i], (a0 + a1) + (a2 + a3));
}

__global__ void k_rsq(float* __restrict__ d) {
  const int i = blockIdx.x * 256 + threadIdx.x;
  d[i] = 1.0f / sqrtf(d[i]);
}

// ---------------------------------------------------------------------------
// L[b,i,j] = (i==j) - exp(-d2_ij)*dinv_i*dinv_j   (bf16)
// ---------------------------------------------------------------------------
__global__ __launch_bounds__(256) void k_lap(const float* __restrict__ x,
                                             const float* __restrict__ dinv,
                                             u16* __restrict__ Lm) {
  const int b = blockIdx.z;
  const int i0 = blockIdx.y * 32;
  const int j0 = blockIdx.x * 256;
  __shared__ float xi[32][FIN];
  __shared__ float di[32];
  const int t = threadIdx.x;
  const float* xb = x + (size_t)b * NN * FIN;
  if (t < 32 * FIN) ((float*)xi)[t] = xb[i0 * FIN + t];
  if (t >= 224) di[t - 224] = dinv[b * NN + i0 + (t - 224)];
  const int j = j0 + t;
  float xj[FIN];
#pragma unroll
  for (int f = 0; f < FIN; ++f) xj[f] = xb[j * FIN + f];
  float sqj = 0.f;
#pragma unroll
  for (int f = 0; f < FIN; ++f) sqj = fmaf(xj[f], xj[f], sqj);
  const float dj = dinv[b * NN + j];
  __syncthreads();
  u16* Lb = Lm + (size_t)b * NN * NN;
#pragma unroll 4
  for (int ii = 0; ii < 32; ++ii) {
    float sqi = 0.f, dot = 0.f;
#pragma unroll
    for (int f = 0; f < FIN; ++f) {
      const float v = xi[ii][f];
      sqi = fmaf(v, v, sqi);
      dot = fmaf(v, xj[f], dot);
    }
    float val = -__expf(2.f * dot - sqi - sqj) * di[ii] * dj;
    if (i0 + ii == j) val += 1.f;
    stf(&Lb[(size_t)(i0 + ii) * NN + j], val);
  }
}

// ---------------------------------------------------------------------------
__global__ void k_h0T(const float* __restrict__ x, const int* __restrict__ cat,
                      u16* __restrict__ T1T) {
  const int c = blockIdx.y;
  const int m = blockIdx.x * 256 + threadIdx.x;
  float v;
  if (c < 6) v = x[(size_t)m * 6 + c];
  else v = (cat[m >> 11] == (c - 6)) ? 1.f : 0.f;
  stf(&T1T[(size_t)c * MTOT + m], v);
}

// weight transpose: fp32 [R][C] -> bf16 [C][ldo] (cols >= R zero-padded by memset)
__global__ void k_wt(const float* __restrict__ in, u16* __restrict__ out,
                     int R, int C, int ldo) {
  const int r = blockIdx.x * 256 + threadIdx.x;
  const int c = blockIdx.y;
  if (r < R) stf(&out[(size_t)c * ldo + r], in[(size_t)r * C + c]);
}

// activation transpose: bf16 [F][Mt] -> bf16 [Mt][ldo]
__global__ __launch_bounds__(256) void k_actT(const u16* __restrict__ in,
                                              u16* __restrict__ out, int F, int ldo) {
  __shared__ u16 t[64][70];
  const int m0 = blockIdx.x * 64;
  const int f0 = blockIdx.y * 64;
  const int tid = threadIdx.x;
#pragma unroll
  for (int v = 0; v < 4; ++v) {
    const int flat = v * 256 + tid;
    const int fr = flat >> 4;
    const int mq = (flat & 15) * 4;
    ushort4 val = {0, 0, 0, 0};
    if (f0 + fr < F) val = *(const ushort4*)&in[(size_t)(f0 + fr) * MTOT + m0 + mq];
    t[fr][mq + 0] = val.x; t[fr][mq + 1] = val.y;
    t[fr][mq + 2] = val.z; t[fr][mq + 3] = val.w;
  }
  __syncthreads();
#pragma unroll
  for (int v = 0; v < 4; ++v) {
    const int flat = v * 256 + tid;
    const int mr = flat >> 4;
    const int fq = (flat & 15) * 4;
    if (f0 + fq >= F) continue;
    u16* dst = &out[(size_t)(m0 + mr) * ldo + f0 + fq];
    if (f0 + fq + 3 < F) {
      ushort4 o;
      o.x = t[fq + 0][mr]; o.y = t[fq + 1][mr];
      o.z = t[fq + 2][mr]; o.w = t[fq + 3][mr];
      *(ushort4*)dst = o;
    } else {
#pragma unroll
      for (int e = 0; e < 4; ++e)
        if (f0 + fq + e < F) dst[e] = t[fq + e][mr];
    }
  }
}

// ---------------------------------------------------------------------------
// MFMA GEMM via global_load_lds, depth-2 counted-vmcnt pipeline (T4):
//   prologue: STAGE(0,b0); STAGE(1,b1); vmcnt(LP); barrier
//   iter t:   compute(buf[t&1]); barrier;
//             STAGE(t+2, buf[t&1]); vmcnt(LP) [else 0]; barrier
// stage(t+1) thus has ~2 full iterations to land before its compute.
// Loads are row-CLAMPED (not skipped) so every wave issues exactly LP loads
// per stage (counted vmcnt needs uniform counts); out-of-range rows produce
// garbage rows in LDS whose MFMA outputs are discarded by the store guards.
// Requires K%64==0, row leading dims %8==0. LDS XOR-swizzle via pre-swizzled
// per-lane SOURCE address. Out[jj*ldo+ii] ([j][i-fast], mfma C layout).
// EPI 0: alpha*acc+beta*Prev; EPI 1: relu(acc+bias+br).
// TWOQ: K-tiles t<ksplitT from Q0, else Q1.
// ---------------------------------------------------------------------------
template <int BM, int BN, int EPI, bool TWOQ, typename OT>
__global__ __launch_bounds__(256) void k_mmL(
    const u16* __restrict__ P, long ldp, int rowsP, long strideP,
    const u16* __restrict__ Q0, long ldq0,
    const u16* __restrict__ Q1, long ldq1, int ksplitT,
    int rowsQ, long strideQ, int K,
    OT* __restrict__ Out, long ldo, long strideO,
    const u16* __restrict__ Prev, float alpha, float beta,
    const float* __restrict__ bias, const float* __restrict__ br, int biasOnI) {
  const int b = blockIdx.z;
  const int i0 = blockIdx.y * BM;
  const int j0 = blockIdx.x * BN;
  const u16* Pb = P + (size_t)b * strideP;
  const u16* Qb0 = Q0 + (size_t)b * strideQ;
  OT* Ob = Out + (size_t)b * strideO;
  const u16* Vb = Prev ? Prev + (size_t)b * strideO : nullptr;

  __shared__ __align__(16) u16 Ps[2][BM * 64];
  __shared__ __align__(16) u16 Qs[2][BN * 64];
  const int tid = threadIdx.x;
  const int lane = tid & 63;
  const int w = tid >> 6;
  const int wr = w >> 1, wc = w & 1;
  constexpr int FI = BM / 32;
  constexpr int FJ = BN / 32;
  constexpr int VP = BM / 32;   // P chunks per wave
  constexpr int VQ = BN / 32;
  constexpr int LP = VP + VQ;   // global_load_lds instrs per stage per wave
  const int rl = lane >> 3;                    // row within 8-row chunk
  const int kb = (((lane & 7) ^ rl) << 3);     // pre-swizzled k-group (elements)

  const u16* prow[VP];
#pragma unroll
  for (int v = 0; v < VP; ++v) {
    const int c = w + v * 4;
    int gr = i0 + c * 8 + rl;
    if (gr >= rowsP) gr = rowsP - 1;           // clamp: uniform load count
    prow[v] = Pb + (size_t)gr * ldp + kb;
  }
  const u16* qrow[VQ];
  const u16* qrow1[TWOQ ? VQ : 1];
#pragma unroll
  for (int v = 0; v < VQ; ++v) {
    const int c = w + v * 4;
    int gr = j0 + c * 8 + rl;
    if (gr >= rowsQ) gr = rowsQ - 1;
    qrow[v] = Qb0 + (size_t)gr * ldq0 + kb;
    if (TWOQ) qrow1[v] = Q1 + (size_t)b * strideQ + (size_t)gr * ldq1 + kb;
  }

  f32x4 acc[FI][FJ];
#pragma unroll
  for (int i = 0; i < FI; ++i)
#pragma unroll
    for (int j = 0; j < FJ; ++j) acc[i][j] = (f32x4){0.f, 0.f, 0.f, 0.f};

  auto stage = [&](int t, int buf) {
#pragma unroll
    for (int v = 0; v < VP; ++v)
      gload16(prow[v] + t * 64, &Ps[buf][(w + v * 4) * 512]);
    if (TWOQ) {
      const bool r1 = (t >= ksplitT);
      const int tq = r1 ? (t - ksplitT) : t;
#pragma unroll
      for (int v = 0; v < VQ; ++v)
        gload16((r1 ? qrow1[v] : qrow[v]) + tq * 64, &Qs[buf][(w + v * 4) * 512]);
    } else {
#pragma unroll
      for (int v = 0; v < VQ; ++v)
        gload16(qrow[v] + t * 64, &Qs[buf][(w + v * 4) * 512]);
    }
  };

  auto compute = [&](int buf) {
#pragma unroll
    for (int h = 0; h < 2; ++h) {
      short8 pf[FI], qf[FJ];
#pragma unroll
      for (int i = 0; i < FI; ++i) {
        const int r = wr * (BM / 2) + i * 16 + (lane & 15);
        const int c = (h * 32 + ((lane >> 4) * 8)) ^ ((r & 7) << 3);
        pf[i] = *(const short8*)&Ps[buf][r * 64 + c];
      }
#pragma unroll
      for (int j = 0; j < FJ; ++j) {
        const int r = wc * (BN / 2) + j * 16 + (lane & 15);
        const int c = (h * 32 + ((lane >> 4) * 8)) ^ ((r & 7) << 3);
        qf[j] = *(const short8*)&Qs[buf][r * 64 + c];
      }
#pragma unroll
      for (int i = 0; i < FI; ++i)
#pragma unroll
        for (int j = 0; j < FJ; ++j)
          acc[i][j] = __builtin_amdgcn_mfma_f32_16x16x32_bf16(pf[i], qf[j], acc[i][j], 0, 0, 0);
    }
  };

  const int nt = K >> 6;   // >= 2 for all our shapes
  // prologue: fill both buffers (2 stages in flight), wait for stage(0)
  stage(0, 0);
  stage(1, 1);
  wait_vmcnt<LP>();                       // stage(0) landed (oldest retired first)
  __builtin_amdgcn_s_barrier();
  __builtin_amdgcn_sched_barrier(0);
  for (int t = 0; t < nt; ++t) {
    const int cur = t & 1;
    compute(cur);
    __builtin_amdgcn_s_barrier();         // all waves done READING buf[cur]
    __builtin_amdgcn_sched_barrier(0);
    if (t + 2 < nt) {
      stage(t + 2, cur);                  // overwrite freed buffer
      wait_vmcnt<LP>();                   // stage(t+1) landed; t+2 stays in flight
    } else {
      wait_vmcnt<0>();                    // tail: drain remaining
    }
    __builtin_amdgcn_s_barrier();         // all waves' next-tile data visible
    __builtin_amdgcn_sched_barrier(0);
  }

  const int ibase = i0 + wr * (BM / 2);
  const int jbase = j0 + wc * (BN / 2);
#pragma unroll
  for (int j = 0; j < FJ; ++j) {
    const int jj = jbase + j * 16 + (lane & 15);
    if (jj >= rowsQ) continue;
    float bj = 0.f;
    if (EPI == 1 && !biasOnI) bj = bias[jj] + br[jj];
#pragma unroll
    for (int i = 0; i < FI; ++i) {
      const int ii = ibase + i * 16 + ((lane >> 4) << 2);
      f32x4 a = acc[i][j];
      float v[4];
#pragma unroll
      for (int e = 0; e < 4; ++e) {
        float xv = a[e];
        if (EPI == 0) {
          xv *= alpha;
          if (beta != 0.f) xv = fmaf(beta, ldf(&Vb[(size_t)jj * ldo + ii + e]), xv);
        } else {
          float bb = bj;
          if (biasOnI) bb = (ii + e < rowsP) ? (bias[ii + e] + br[ii + e]) : 0.f;
          xv = fmaxf(xv + bb, 0.f);
        }
        v[e] = xv;
      }
      if constexpr (sizeof(OT) == 2) {
        u16* dst = (u16*)&Ob[(size_t)jj * ldo + ii];
        if (ii + 3 < rowsP) {
          ushort4 o; o.x = tobf(v[0]); o.y = tobf(v[1]); o.z = tobf(v[2]); o.w = tobf(v[3]);
          *(ushort4*)dst = o;
        } else {
#pragma unroll
          for (int e = 0; e < 4; ++e) if (ii + e < rowsP) dst[e] = tobf(v[e]);
        }
      } else {
        float* dst = (float*)&Ob[(size_t)jj * ldo + ii];
#pragma unroll
        for (int e = 0; e < 4; ++e) if (ii + e < rowsP) dst[e] = v[e];
      }
    }
  }
}

// ---------------------------------------------------------------------------
extern "C" void kernel_launch(void* const* d_in, const int* in_sizes, int n_in,
                              void* d_out, int out_size, void* d_ws, size_t ws_size,
                              hipStream_t stream) {
  const float* x    = (const float*)d_in[0];
  const int*   cat  = (const int*)  d_in[1];
  const float* W1   = (const float*)d_in[2];
  const float* b1   = (const float*)d_in[3];
  const float* W2   = (const float*)d_in[4];
  const float* b2   = (const float*)d_in[5];
  const float* W3   = (const float*)d_in[6];
  const float* b3   = (const float*)d_in[7];
  const float* fc1w = (const float*)d_in[8];
  const float* fc1b = (const float*)d_in[9];
  const float* fc2w = (const float*)d_in[10];
  const float* fc2b = (const float*)d_in[11];
  const float* fc3w = (const float*)d_in[12];
  const float* fc3b = (const float*)d_in[13];
  const float* br0  = (const float*)d_in[14];
  const float* br1  = (const float*)d_in[15];
  const float* br2  = (const float*)d_in[16];
  const float* br3  = (const float*)d_in[17];
  const float* br4  = (const float*)d_in[18];
  const float* br5  = (const float*)d_in[19];

  if (ws_size < 240054784ull) return;  // fail loudly

  u16* ws = (u16*)d_ws;
  u16* Wt1p = ws;                    // [128][192]  (K padded 132->192, zero tail)
  u16* Wt2  = Wt1p + 24576;          // [512][640]
  u16* Wt3  = Wt2 + 327680;          // [1024][1536]
  u16* Wtf1 = Wt3 + 1572864;         // [512][1024]
  u16* Wtf2 = Wtf1 + 524288;         // [128][1024]
  u16* Wtf3 = Wtf2 + 131072;         // [50][128]
  u16* Lbuf = ws + 2586880;          // [16][2048][2048] -> later L3rm [M][1536]
  u16* ACT  = Lbuf + 67108864;       // 50,331,648 elems

  float* dinv = (float*)ACT;         // dead before T1T written
  u16* T1T   = ACT;                  // [132][M]
  u16* L1rm  = ACT + 4325376;        // [M][192] (cols 132..191 zero)
  u16* T2T   = ACT;                  // [640][M]
  u16* L2rm  = ACT + 20971520;       // [M][640]
  u16* T3T   = ACT;                  // [1536][M]
  u16* L3rm  = Lbuf;                 // [M][1536]
  u16* h3rm  = ACT;                  // [M][1024]
  u16* fc1o  = ACT + 33554432;       // [M][512]
  u16* h5    = ACT;                  // [M][128]

  const long MT = MTOT;
  const int BIG = 1 << 28;

  // zero-init: dinv accumulator, padded W1, padded L1rm
  hipMemsetAsync(dinv, 0, (size_t)MTOT * 4, stream);
  hipMemsetAsync(Wt1p, 0, 24576 * 2, stream);
  hipMemsetAsync(L1rm, 0, (size_t)MTOT * 192 * 2, stream);

  // weights -> bf16 transposed
  k_wt<<<dim3(1, 128), 256, 0, stream>>>(W1, Wt1p, 132, 128, 192);
  k_wt<<<dim3(3, 512), 256, 0, stream>>>(W2, Wt2, 640, 512, 640);
  k_wt<<<dim3(6, 1024), 256, 0, stream>>>(W3, Wt3, 1536, 1024, 1536);
  k_wt<<<dim3(4, 512), 256, 0, stream>>>(fc1w, Wtf1, 1024, 512, 1024);
  k_wt<<<dim3(4, 128), 256, 0, stream>>>(fc2w, Wtf2, 1024, 128, 1024);
  k_wt<<<dim3(1, 50), 256, 0, stream>>>(fc3w, Wtf3, 128, 50, 128);

  // Laplacian (bf16)
  k_dpart<<<dim3(8, BB, 4), 256, 0, stream>>>(x, dinv);
  k_rsq<<<dim3(MTOT / 256), 256, 0, stream>>>(dinv);
  k_lap<<<dim3(8, 64, BB), 256, 0, stream>>>(x, dinv, Lbuf);

  // ---- layer 1: 6 slots of 22 rows in T1T ----
  k_h0T<<<dim3(128, 22), 256, 0, stream>>>(x, cat, T1T);
  {
    const size_t s = (size_t)22 * MT;
    k_mmL<64, 32, 0, false, u16><<<dim3(1, 32, BB), 256, 0, stream>>>(
        Lbuf, NN, NN, (long)NN * NN, T1T, MT, nullptr, 0, BIG, 22, NN,
        NN, T1T + s, MT, NN, nullptr, 1.f, 0.f, nullptr, nullptr, 0);
    for (int k = 2; k < 6; ++k)
      k_mmL<64, 32, 0, false, u16><<<dim3(1, 32, BB), 256, 0, stream>>>(
          Lbuf, NN, NN, (long)NN * NN, T1T + (k - 1) * s, MT, nullptr, 0, BIG, 22, NN,
          NN, T1T + k * s, MT, NN, T1T + (k - 2) * s, 2.f, -1.f, nullptr, nullptr, 0);
  }
  k_actT<<<dim3(512, 3), 256, 0, stream>>>(T1T, L1rm, 132, 192);
  // combine1 (K padded to 192) -> T2T slot0 (transposed)
  k_mmL<128, 128, 1, false, u16><<<dim3(1, 256, 1), 256, 0, stream>>>(
      L1rm, 192, MTOT, 0, Wt1p, 192, nullptr, 0, BIG, 128, 0,
      192, T2T, MT, 0, nullptr, 0.f, 0.f, b1, br0, 0);

  // ---- layer 2: 5 slots of 128 rows ----
  {
    const size_t s = (size_t)128 * MT;
    k_mmL<64, 128, 0, false, u16><<<dim3(1, 32, BB), 256, 0, stream>>>(
        Lbuf, NN, NN, (long)NN * NN, T2T, MT, nullptr, 0, BIG, 128, NN,
        NN, T2T + s, MT, NN, nullptr, 1.f, 0.f, nullptr, nullptr, 0);
    for (int k = 2; k < 5; ++k)
      k_mmL<64, 128, 0, false, u16><<<dim3(1, 32, BB), 256, 0, stream>>>(
          Lbuf, NN, NN, (long)NN * NN, T2T + (k - 1) * s, MT, nullptr, 0, BIG, 128, NN,
          NN, T2T + k * s, MT, NN, T2T + (k - 2) * s, 2.f, -1.f, nullptr, nullptr, 0);
  }
  k_actT<<<dim3(512, 10), 256, 0, stream>>>(T2T, L2rm, 640, 640);
  // combine2 -> T3T slot0 (transposed)
  k_mmL<128, 128, 1, false, u16><<<dim3(4, 256, 1), 256, 0, stream>>>(
      L2rm, 640, MTOT, 0, Wt2, 640, nullptr, 0, BIG, 512, 0,
      640, T3T, MT, 0, nullptr, 0.f, 0.f, b2, br1, 0);

  // ---- layer 3: 3 slots of 512 rows ----
  {
    const size_t s = (size_t)512 * MT;
    k_mmL<128, 128, 0, false, u16><<<dim3(4, 16, BB), 256, 0, stream>>>(
        Lbuf, NN, NN, (long)NN * NN, T3T, MT, nullptr, 0, BIG, 512, NN,
        NN, T3T + s, MT, NN, nullptr, 1.f, 0.f, nullptr, nullptr, 0);
    k_mmL<128, 128, 0, false, u16><<<dim3(4, 16, BB), 256, 0, stream>>>(
        Lbuf, NN, NN, (long)NN * NN, T3T + s, MT, nullptr, 0, BIG, 512, NN,
        NN, T3T + 2 * s, MT, NN, T3T, 2.f, -1.f, nullptr, nullptr, 0);
  }
  k_actT<<<dim3(512, 24), 256, 0, stream>>>(T3T, L3rm, 1536, 1536);  // L dead -> Lbuf reused
  // combine3 (fc orientation) -> h3rm [M][1024]
  k_mmL<128, 128, 1, false, u16><<<dim3(256, 8, 1), 256, 0, stream>>>(
      Wt3, 1536, 1024, 0, L3rm, 1536, nullptr, 0, BIG, MTOT, 0,
      1536, h3rm, 1024, 0, nullptr, 0.f, 0.f, b3, br2, 1);

  // fc1 -> fc1o [M][512]
  k_mmL<128, 128, 1, false, u16><<<dim3(256, 4, 1), 256, 0, stream>>>(
      Wtf1, 1024, 512, 0, h3rm, 1024, nullptr, 0, BIG, MTOT, 0,
      1024, fc1o, 512, 0, nullptr, 0.f, 0.f, fc1b, br3, 1);
  // fc2: K 2-region [fc1o | L3rm slot0] -> h5 [M][128]
  k_mmL<64, 128, 1, true, u16><<<dim3(256, 2, 1), 256, 0, stream>>>(
      Wtf2, 1024, 128, 0, fc1o, 512, L3rm, 1536, 8, MTOT, 0,
      1024, h5, 128, 0, nullptr, 0.f, 0.f, fc2b, br4, 1);
  // fc3 -> d_out fp32 [M][50]
  k_mmL<64, 128, 1, false, float><<<dim3(256, 1, 1), 256, 0, stream>>>(
      Wtf3, 128, 50, 0, h5, 128, nullptr, 0, BIG, MTOT, 0,
      128, (float*)d_out, 50, 0, nullptr, 0.f, 0.f, fc3b, br5, 1);
}

// Round 10
// 1094.653 us; speedup vs baseline: 1.0548x; 1.0548x over previous
//
#include <hip/hip_runtime.h>

#define BB 16
#define NN 2048
#define FIN 6
#define MTOT (BB*NN)   // 32768

typedef unsigned short u16;
typedef __attribute__((ext_vector_type(8))) short  short8;
typedef __attribute__((ext_vector_type(4))) float  f32x4;

// ---- bf16 helpers ----------------------------------------------------------
__device__ inline float ldf(const u16* p) {
  unsigned u = ((unsigned)*p) << 16; float f; __builtin_memcpy(&f, &u, 4); return f;
}
__device__ inline u16 tobf(float v) {
  unsigned u; __builtin_memcpy(&u, &v, 4);
  u = (u + 0x7FFFu + ((u >> 16) & 1u)) >> 16;   // RNE
  return (u16)u;
}
__device__ inline void stf(u16* p, float v) { *p = tobf(v); }

// async global->LDS, 16 bytes per lane (dest = wave-uniform base + lane*16)
__device__ __forceinline__ void gload16(const u16* g, u16* l) {
  __builtin_amdgcn_global_load_lds(
      (const __attribute__((address_space(1))) void*)g,
      (__attribute__((address_space(3))) void*)l, 16, 0, 0);
}

// ---------------------------------------------------------------------------
// partial row-sums of adj: dsum[b,i] += sum_{j in chunk} exp(-||x_i-x_j||^2)
// ---------------------------------------------------------------------------
__global__ __launch_bounds__(256) void k_dpart(const float* __restrict__ x,
                                               float* __restrict__ dsum) {
  __shared__ float xs[512][FIN];
  __shared__ float sqs[512];
  const int b = blockIdx.y;
  const int j0 = blockIdx.z * 512;
  const float* xb = x + (size_t)b * NN * FIN;
  for (int l = threadIdx.x; l < 512 * FIN; l += 256) ((float*)xs)[l] = xb[(size_t)j0 * FIN + l];
  __syncthreads();
  for (int j = threadIdx.x; j < 512; j += 256) {
    float s = 0.f;
#pragma unroll
    for (int f = 0; f < FIN; ++f) { float v = xs[j][f]; s = fmaf(v, v, s); }
    sqs[j] = s;
  }
  __syncthreads();
  const int i = blockIdx.x * 256 + threadIdx.x;
  float xi[FIN];
#pragma unroll
  for (int f = 0; f < FIN; ++f) xi[f] = xb[(size_t)i * FIN + f];
  float sqi = 0.f;
#pragma unroll
  for (int f = 0; f < FIN; ++f) sqi = fmaf(xi[f], xi[f], sqi);
  float a0 = 0.f, a1 = 0.f, a2 = 0.f, a3 = 0.f;
  for (int j = 0; j < 512; j += 4) {
#pragma unroll
    for (int u = 0; u < 4; ++u) {
      const int jj = j + u;
      float dot = 0.f;
#pragma unroll
      for (int f = 0; f < FIN; ++f) dot = fmaf(xs[jj][f], xi[f], dot);
      const float e = __expf(2.f * dot - sqi - sqs[jj]);
      if (u == 0) a0 += e; else if (u == 1) a1 += e; else if (u == 2) a2 += e; else a3 += e;
    }
  }
  atomicAdd(&dsum[b * NN + i], (a0 + a1) + (a2 + a3));
}

// ---------------------------------------------------------------------------
// L[b,i,j] = (i==j) - exp(-d2_ij)*rsqrt(dsum_i)*rsqrt(dsum_j)   (bf16)
// 4 j-columns per thread, ushort4 stores. grid (NN/1024, NN/32, BB)
// ---------------------------------------------------------------------------
__global__ __launch_bounds__(256) void k_lap(const float* __restrict__ x,
                                             const float* __restrict__ dsum,
                                             u16* __restrict__ Lm) {
  const int b = blockIdx.z;
  const int i0 = blockIdx.y * 32;
  const int j0 = blockIdx.x * 1024;
  __shared__ float xi[32][FIN];
  __shared__ float di[32];
  const int t = threadIdx.x;
  const float* xb = x + (size_t)b * NN * FIN;
  if (t < 32 * FIN) ((float*)xi)[t] = xb[i0 * FIN + t];
  if (t >= 224) di[t - 224] = 1.0f / sqrtf(dsum[b * NN + i0 + (t - 224)]);
  const int j = j0 + t * 4;
  float xj[4][FIN], sqj[4], dj[4];
#pragma unroll
  for (int u = 0; u < 4; ++u) {
    float s = 0.f;
#pragma unroll
    for (int f = 0; f < FIN; ++f) {
      const float v = xb[(size_t)(j + u) * FIN + f];
      xj[u][f] = v; s = fmaf(v, v, s);
    }
    sqj[u] = s;
    dj[u] = 1.0f / sqrtf(dsum[b * NN + j + u]);
  }
  __syncthreads();
  u16* Lb = Lm + (size_t)b * NN * NN;
#pragma unroll 2
  for (int ii = 0; ii < 32; ++ii) {
    float sqi = 0.f;
#pragma unroll
    for (int f = 0; f < FIN; ++f) { const float v = xi[ii][f]; sqi = fmaf(v, v, sqi); }
    u16 o[4];
#pragma unroll
    for (int u = 0; u < 4; ++u) {
      float dot = 0.f;
#pragma unroll
      for (int f = 0; f < FIN; ++f) dot = fmaf(xi[ii][f], xj[u][f], dot);
      float val = -__expf(2.f * dot - sqi - sqj[u]) * di[ii] * dj[u];
      if (i0 + ii == j + u) val += 1.f;
      o[u] = tobf(val);
    }
    ushort4 ov; ov.x = o[0]; ov.y = o[1]; ov.z = o[2]; ov.w = o[3];
    *(ushort4*)&Lb[(size_t)(i0 + ii) * NN + j] = ov;
  }
}

// ---------------------------------------------------------------------------
__global__ void k_h0T(const float* __restrict__ x, const int* __restrict__ cat,
                      u16* __restrict__ T1T) {
  const int c = blockIdx.y;
  const int m = blockIdx.x * 256 + threadIdx.x;
  float v;
  if (c < 6) v = x[(size_t)m * 6 + c];
  else v = (cat[m >> 11] == (c - 6)) ? 1.f : 0.f;
  stf(&T1T[(size_t)c * MTOT + m], v);
}

// weight transpose: fp32 [R][C] -> bf16 [C][ldo] (cols >= R zero-padded by memset)
__global__ void k_wt(const float* __restrict__ in, u16* __restrict__ out,
                     int R, int C, int ldo) {
  const int r = blockIdx.x * 256 + threadIdx.x;
  const int c = blockIdx.y;
  if (r < R) stf(&out[(size_t)c * ldo + r], in[(size_t)r * C + c]);
}

// activation transpose: bf16 [F][Mt] -> bf16 [Mt][ldo]; cols F..Fw-1 zero-filled
__global__ __launch_bounds__(256) void k_actT(const u16* __restrict__ in,
                                              u16* __restrict__ out, int F,
                                              int ldo, int Fw) {
  __shared__ u16 t[64][70];
  const int m0 = blockIdx.x * 64;
  const int f0 = blockIdx.y * 64;
  const int tid = threadIdx.x;
#pragma unroll
  for (int v = 0; v < 4; ++v) {
    const int flat = v * 256 + tid;
    const int fr = flat >> 4;
    const int mq = (flat & 15) * 4;
    ushort4 val = {0, 0, 0, 0};
    if (f0 + fr < F) val = *(const ushort4*)&in[(size_t)(f0 + fr) * MTOT + m0 + mq];
    t[fr][mq + 0] = val.x; t[fr][mq + 1] = val.y;
    t[fr][mq + 2] = val.z; t[fr][mq + 3] = val.w;
  }
  __syncthreads();
#pragma unroll
  for (int v = 0; v < 4; ++v) {
    const int flat = v * 256 + tid;
    const int mr = flat >> 4;
    const int fq = (flat & 15) * 4;
    if (f0 + fq >= Fw) continue;
    u16* dst = &out[(size_t)(m0 + mr) * ldo + f0 + fq];
    if (f0 + fq + 3 < Fw) {
      ushort4 o;
      o.x = t[fq + 0][mr]; o.y = t[fq + 1][mr];
      o.z = t[fq + 2][mr]; o.w = t[fq + 3][mr];
      *(ushort4*)dst = o;
    } else {
#pragma unroll
      for (int e = 0; e < 4; ++e)
        if (f0 + fq + e < Fw) dst[e] = t[fq + e][mr];
    }
  }
}

// ---------------------------------------------------------------------------
// MFMA GEMM via global_load_lds (round-7 structure: single buffer, 2 barriers)
// + chunked XCD swizzle: SWZ=0 none; SWZ=1 natural order (x,y fastest — cheb);
// SWZ=2 y-fastest logical order (combine/fc, z==1). Each XCD then processes a
// contiguous logical chunk containing complete operand-panel sharing groups.
// Requires K%64==0, row leading dims %8==0. LDS XOR-swizzle via pre-swizzled
// per-lane SOURCE address. Out[jj*ldo+ii] ([j][i-fast], mfma C layout).
// EPI 0: alpha*acc+beta*Prev; EPI 1: relu(acc+bias+br).
// TWOQ: K-tiles t<ksplitT from Q0, else Q1.
// ---------------------------------------------------------------------------
template <int BM, int BN, int EPI, bool TWOQ, int SWZ, typename OT>
__global__ __launch_bounds__(256) void k_mmL(
    const u16* __restrict__ P, long ldp, int rowsP, long strideP,
    const u16* __restrict__ Q0, long ldq0,
    const u16* __restrict__ Q1, long ldq1, int ksplitT,
    int rowsQ, long strideQ, int K,
    OT* __restrict__ Out, long ldo, long strideO,
    const u16* __restrict__ Prev, float alpha, float beta,
    const float* __restrict__ bias, const float* __restrict__ br, int biasOnI) {
  int bx = blockIdx.x, by = blockIdx.y, bz = blockIdx.z;
  if (SWZ != 0) {
    const int gx = gridDim.x, gy = gridDim.y;
    const int nwg = gx * gy * gridDim.z;     // all launches: nwg % 8 == 0
    const int o = bx + gx * (by + gy * bz);
    const int Lg = (o & 7) * (nwg >> 3) + (o >> 3);
    if (SWZ == 1) { bx = Lg % gx; by = (Lg / gx) % gy; bz = Lg / (gx * gy); }
    else          { by = Lg % gy; bx = (Lg / gy) % gx; bz = Lg / (gx * gy); }
  }
  const int b = bz;
  const int i0 = by * BM;
  const int j0 = bx * BN;
  const u16* Pb = P + (size_t)b * strideP;
  const u16* Qb0 = Q0 + (size_t)b * strideQ;
  OT* Ob = Out + (size_t)b * strideO;
  const u16* Vb = Prev ? Prev + (size_t)b * strideO : nullptr;

  __shared__ __align__(16) u16 Ps[BM * 64];
  __shared__ __align__(16) u16 Qs[BN * 64];
  const int tid = threadIdx.x;
  const int lane = tid & 63;
  const int w = tid >> 6;
  const int wr = w >> 1, wc = w & 1;
  constexpr int FI = BM / 32;
  constexpr int FJ = BN / 32;
  constexpr int VP = BM / 32;   // P chunks per wave
  constexpr int VQ = BN / 32;
  const int rl = lane >> 3;                    // row within 8-row chunk
  const int kb = (((lane & 7) ^ rl) << 3);     // pre-swizzled k-group (elements)

  const u16* prow[VP];
  bool pok[VP];
#pragma unroll
  for (int v = 0; v < VP; ++v) {
    const int c = w + v * 4;
    const int gr = i0 + c * 8 + rl;
    pok[v] = gr < rowsP;
    prow[v] = Pb + (size_t)gr * ldp + kb;
  }
  const u16* qrow[VQ];
  const u16* qrow1[TWOQ ? VQ : 1];
  bool qok[VQ];
#pragma unroll
  for (int v = 0; v < VQ; ++v) {
    const int c = w + v * 4;
    const int gr = j0 + c * 8 + rl;
    qok[v] = gr < rowsQ;
    qrow[v] = Qb0 + (size_t)gr * ldq0 + kb;
    if (TWOQ) qrow1[v] = Q1 + (size_t)b * strideQ + (size_t)gr * ldq1 + kb;
  }

  f32x4 acc[FI][FJ];
#pragma unroll
  for (int i = 0; i < FI; ++i)
#pragma unroll
    for (int j = 0; j < FJ; ++j) acc[i][j] = (f32x4){0.f, 0.f, 0.f, 0.f};

  const int nt = K >> 6;
  for (int t = 0; t < nt; ++t) {
#pragma unroll
    for (int v = 0; v < VP; ++v)
      if (pok[v]) gload16(prow[v] + t * 64, &Ps[(w + v * 4) * 512]);
    if (TWOQ) {
      const bool r1 = (t >= ksplitT);
      const int tq = r1 ? (t - ksplitT) : t;
#pragma unroll
      for (int v = 0; v < VQ; ++v)
        if (qok[v]) gload16((r1 ? qrow1[v] : qrow[v]) + tq * 64, &Qs[(w + v * 4) * 512]);
    } else {
#pragma unroll
      for (int v = 0; v < VQ; ++v)
        if (qok[v]) gload16(qrow[v] + t * 64, &Qs[(w + v * 4) * 512]);
    }
    __syncthreads();   // drains vmcnt -> LDS ready
#pragma unroll
    for (int h = 0; h < 2; ++h) {
      short8 pf[FI], qf[FJ];
#pragma unroll
      for (int i = 0; i < FI; ++i) {
        const int r = wr * (BM / 2) + i * 16 + (lane & 15);
        const int c = (h * 32 + ((lane >> 4) * 8)) ^ ((r & 7) << 3);
        pf[i] = *(const short8*)&Ps[r * 64 + c];
      }
#pragma unroll
      for (int j = 0; j < FJ; ++j) {
        const int r = wc * (BN / 2) + j * 16 + (lane & 15);
        const int c = (h * 32 + ((lane >> 4) * 8)) ^ ((r & 7) << 3);
        qf[j] = *(const short8*)&Qs[r * 64 + c];
      }
#pragma unroll
      for (int i = 0; i < FI; ++i)
#pragma unroll
        for (int j = 0; j < FJ; ++j)
          acc[i][j] = __builtin_amdgcn_mfma_f32_16x16x32_bf16(pf[i], qf[j], acc[i][j], 0, 0, 0);
    }
    __syncthreads();
  }

  const int ibase = i0 + wr * (BM / 2);
  const int jbase = j0 + wc * (BN / 2);
#pragma unroll
  for (int j = 0; j < FJ; ++j) {
    const int jj = jbase + j * 16 + (lane & 15);
    if (jj >= rowsQ) continue;
    float bj = 0.f;
    if (EPI == 1 && !biasOnI) bj = bias[jj] + br[jj];
#pragma unroll
    for (int i = 0; i < FI; ++i) {
      const int ii = ibase + i * 16 + ((lane >> 4) << 2);
      f32x4 a = acc[i][j];
      float v[4];
#pragma unroll
      for (int e = 0; e < 4; ++e) {
        float xv = a[e];
        if (EPI == 0) {
          xv *= alpha;
          if (beta != 0.f) xv = fmaf(beta, ldf(&Vb[(size_t)jj * ldo + ii + e]), xv);
        } else {
          float bb = bj;
          if (biasOnI) bb = (ii + e < rowsP) ? (bias[ii + e] + br[ii + e]) : 0.f;
          xv = fmaxf(xv + bb, 0.f);
        }
        v[e] = xv;
      }
      if constexpr (sizeof(OT) == 2) {
        u16* dst = (u16*)&Ob[(size_t)jj * ldo + ii];
        if (ii + 3 < rowsP) {
          ushort4 o; o.x = tobf(v[0]); o.y = tobf(v[1]); o.z = tobf(v[2]); o.w = tobf(v[3]);
          *(ushort4*)dst = o;
        } else {
#pragma unroll
          for (int e = 0; e < 4; ++e) if (ii + e < rowsP) dst[e] = tobf(v[e]);
        }
      } else {
        float* dst = (float*)&Ob[(size_t)jj * ldo + ii];
#pragma unroll
        for (int e = 0; e < 4; ++e) if (ii + e < rowsP) dst[e] = v[e];
      }
    }
  }
}

// ---------------------------------------------------------------------------
extern "C" void kernel_launch(void* const* d_in, const int* in_sizes, int n_in,
                              void* d_out, int out_size, void* d_ws, size_t ws_size,
                              hipStream_t stream) {
  const float* x    = (const float*)d_in[0];
  const int*   cat  = (const int*)  d_in[1];
  const float* W1   = (const float*)d_in[2];
  const float* b1   = (const float*)d_in[3];
  const float* W2   = (const float*)d_in[4];
  const float* b2   = (const float*)d_in[5];
  const float* W3   = (const float*)d_in[6];
  const float* b3   = (const float*)d_in[7];
  const float* fc1w = (const float*)d_in[8];
  const float* fc1b = (const float*)d_in[9];
  const float* fc2w = (const float*)d_in[10];
  const float* fc2b = (const float*)d_in[11];
  const float* fc3w = (const float*)d_in[12];
  const float* fc3b = (const float*)d_in[13];
  const float* br0  = (const float*)d_in[14];
  const float* br1  = (const float*)d_in[15];
  const float* br2  = (const float*)d_in[16];
  const float* br3  = (const float*)d_in[17];
  const float* br4  = (const float*)d_in[18];
  const float* br5  = (const float*)d_in[19];

  if (ws_size < 240054784ull) return;  // fail loudly

  u16* ws = (u16*)d_ws;
  u16* Wt1p = ws;                    // [128][192]  (K padded 132->192, zero tail)
  u16* Wt2  = Wt1p + 24576;          // [512][640]
  u16* Wt3  = Wt2 + 327680;          // [1024][1536]
  u16* Wtf1 = Wt3 + 1572864;         // [512][1024]
  u16* Wtf2 = Wtf1 + 524288;         // [128][1024]
  u16* Wtf3 = Wtf2 + 131072;         // [50][128]
  u16* Lbuf = ws + 2586880;          // [16][2048][2048] -> later L3rm [M][1536]
  u16* ACT  = Lbuf + 67108864;       // 50,331,648 elems

  float* dsum = (float*)ACT;         // dead before T1T written
  u16* T1T   = ACT;                  // [132][M]
  u16* L1rm  = ACT + 4325376;        // [M][192] (cols 132..191 zero-filled by actT)
  u16* T2T   = ACT;                  // [640][M]
  u16* L2rm  = ACT + 20971520;       // [M][640]
  u16* T3T   = ACT;                  // [1536][M]
  u16* L3rm  = Lbuf;                 // [M][1536]
  u16* h3rm  = ACT;                  // [M][1024]
  u16* fc1o  = ACT + 33554432;       // [M][512]
  u16* h5    = ACT;                  // [M][128]

  const long MT = MTOT;
  const int BIG = 1 << 28;

  // zero-init: dsum accumulator, padded W1
  hipMemsetAsync(dsum, 0, (size_t)MTOT * 4, stream);
  hipMemsetAsync(Wt1p, 0, 24576 * 2, stream);

  // weights -> bf16 transposed
  k_wt<<<dim3(1, 128), 256, 0, stream>>>(W1, Wt1p, 132, 128, 192);
  k_wt<<<dim3(3, 512), 256, 0, stream>>>(W2, Wt2, 640, 512, 640);
  k_wt<<<dim3(6, 1024), 256, 0, stream>>>(W3, Wt3, 1536, 1024, 1536);
  k_wt<<<dim3(4, 512), 256, 0, stream>>>(fc1w, Wtf1, 1024, 512, 1024);
  k_wt<<<dim3(4, 128), 256, 0, stream>>>(fc2w, Wtf2, 1024, 128, 1024);
  k_wt<<<dim3(1, 50), 256, 0, stream>>>(fc3w, Wtf3, 128, 50, 128);

  // Laplacian (bf16); k_lap applies rsqrt to raw sums itself
  k_dpart<<<dim3(8, BB, 4), 256, 0, stream>>>(x, dsum);
  k_lap<<<dim3(2, 64, BB), 256, 0, stream>>>(x, dsum, Lbuf);

  // ---- layer 1: 6 slots of 22 rows in T1T ----
  k_h0T<<<dim3(128, 22), 256, 0, stream>>>(x, cat, T1T);
  {
    const size_t s = (size_t)22 * MT;
    k_mmL<64, 32, 0, false, 1, u16><<<dim3(1, 32, BB), 256, 0, stream>>>(
        Lbuf, NN, NN, (long)NN * NN, T1T, MT, nullptr, 0, BIG, 22, NN,
        NN, T1T + s, MT, NN, nullptr, 1.f, 0.f, nullptr, nullptr, 0);
    for (int k = 2; k < 6; ++k)
      k_mmL<64, 32, 0, false, 1, u16><<<dim3(1, 32, BB), 256, 0, stream>>>(
          Lbuf, NN, NN, (long)NN * NN, T1T + (k - 1) * s, MT, nullptr, 0, BIG, 22, NN,
          NN, T1T + k * s, MT, NN, T1T + (k - 2) * s, 2.f, -1.f, nullptr, nullptr, 0);
  }
  k_actT<<<dim3(512, 3), 256, 0, stream>>>(T1T, L1rm, 132, 192, 192);
  // combine1 (K padded to 192) -> T2T slot0 (transposed)
  k_mmL<128, 128, 1, false, 2, u16><<<dim3(1, 256, 1), 256, 0, stream>>>(
      L1rm, 192, MTOT, 0, Wt1p, 192, nullptr, 0, BIG, 128, 0,
      192, T2T, MT, 0, nullptr, 0.f, 0.f, b1, br0, 0);

  // ---- layer 2: 5 slots of 128 rows ----
  {
    const size_t s = (size_t)128 * MT;
    k_mmL<64, 128, 0, false, 1, u16><<<dim3(1, 32, BB), 256, 0, stream>>>(
        Lbuf, NN, NN, (long)NN * NN, T2T, MT, nullptr, 0, BIG, 128, NN,
        NN, T2T + s, MT, NN, nullptr, 1.f, 0.f, nullptr, nullptr, 0);
    for (int k = 2; k < 5; ++k)
      k_mmL<64, 128, 0, false, 1, u16><<<dim3(1, 32, BB), 256, 0, stream>>>(
          Lbuf, NN, NN, (long)NN * NN, T2T + (k - 1) * s, MT, nullptr, 0, BIG, 128, NN,
          NN, T2T + k * s, MT, NN, T2T + (k - 2) * s, 2.f, -1.f, nullptr, nullptr, 0);
  }
  k_actT<<<dim3(512, 10), 256, 0, stream>>>(T2T, L2rm, 640, 640, 640);
  // combine2 -> T3T slot0 (transposed)
  k_mmL<128, 128, 1, false, 2, u16><<<dim3(4, 256, 1), 256, 0, stream>>>(
      L2rm, 640, MTOT, 0, Wt2, 640, nullptr, 0, BIG, 512, 0,
      640, T3T, MT, 0, nullptr, 0.f, 0.f, b2, br1, 0);

  // ---- layer 3: 3 slots of 512 rows ----
  {
    const size_t s = (size_t)512 * MT;
    k_mmL<128, 128, 0, false, 1, u16><<<dim3(4, 16, BB), 256, 0, stream>>>(
        Lbuf, NN, NN, (long)NN * NN, T3T, MT, nullptr, 0, BIG, 512, NN,
        NN, T3T + s, MT, NN, nullptr, 1.f, 0.f, nullptr, nullptr, 0);
    k_mmL<128, 128, 0, false, 1, u16><<<dim3(4, 16, BB), 256, 0, stream>>>(
        Lbuf, NN, NN, (long)NN * NN, T3T + s, MT, nullptr, 0, BIG, 512, NN,
        NN, T3T + 2 * s, MT, NN, T3T, 2.f, -1.f, nullptr, nullptr, 0);
  }
  k_actT<<<dim3(512, 24), 256, 0, stream>>>(T3T, L3rm, 1536, 1536, 1536);  // Lbuf reused
  // combine3 (fc orientation) -> h3rm [M][1024]
  k_mmL<128, 128, 1, false, 2, u16><<<dim3(256, 8, 1), 256, 0, stream>>>(
      Wt3, 1536, 1024, 0, L3rm, 1536, nullptr, 0, BIG, MTOT, 0,
      1536, h3rm, 1024, 0, nullptr, 0.f, 0.f, b3, br2, 1);

  // fc1 -> fc1o [M][512]
  k_mmL<128, 128, 1, false, 2, u16><<<dim3(256, 4, 1), 256, 0, stream>>>(
      Wtf1, 1024, 512, 0, h3rm, 1024, nullptr, 0, BIG, MTOT, 0,
      1024, fc1o, 512, 0, nullptr, 0.f, 0.f, fc1b, br3, 1);
  // fc2: K 2-region [fc1o | L3rm slot0] -> h5 [M][128]
  k_mmL<64, 128, 1, true, 2, u16><<<dim3(256, 2, 1), 256, 0, stream>>>(
      Wtf2, 1024, 128, 0, fc1o, 512, L3rm, 1536, 8, MTOT, 0,
      1024, h5, 128, 0, nullptr, 0.f, 0.f, fc2b, br4, 1);
  // fc3 -> d_out fp32 [M][50]
  k_mmL<64, 128, 1, false, 2, float><<<dim3(256, 1, 1), 256, 0, stream>>>(
      Wtf3, 128, 50, 0, h5, 128, nullptr, 0, BIG, MTOT, 0,
      128, (float*)d_out, 50, 0, nullptr, 0.f, 0.f, fc3b, br5, 1);
}